// Round 3
// baseline (314.889 us; speedup 1.0000x reference)
//
#include <hip/hip_runtime.h>

// MultinomialDiffusion.q_posterior, fixed shapes — ALL FLOAT32 (reference dtypes):
//   log_x_t, log_x_0: (B=16, K=2, 1, 1024, 1024) f32
//   schedules: (1000,) f32 each; t: (16,) int32
//   out: (16, 2, 1, 1024, 1024) f32
// Elementwise + K=2 logsumexp -> HBM-bound: 256 MB read + 128 MB write ≈ 64 us floor.

#define B_DIM 16
#define LL (1024 * 1024)
#define VPB (LL / 4)          // float4 groups per class-plane per batch = 262144

// logaddexp(x,y) = max + log(1 + exp(min-max)); fast intrinsics, rel err ~1e-6
__device__ __forceinline__ float lae(float x, float y) {
    float m = fmaxf(x, y);
    float n = fminf(x, y);
    return m + __logf(1.0f + __expf(n - m));
}

__global__ __launch_bounds__(256) void qposterior_kernel(
    const float* __restrict__ lxt,
    const float* __restrict__ lx0,
    const float* __restrict__ la,
    const float* __restrict__ l1a,
    const float* __restrict__ lab,
    const float* __restrict__ l1ab,
    const int* __restrict__ tarr,
    float* __restrict__ out)
{
    const float LOGK = 0.6931471805599453f; // log(2)

    int gid = blockIdx.x * blockDim.x + threadIdx.x;   // < 16 * 262144 = 2^22
    int b = gid >> 18;                                  // gid / VPB
    int v = gid & (VPB - 1);
    int base = b * (2 * LL) + v * 4;                    // f32 element offset (fits int32)

    // per-batch scalars (wave-uniform: 1024 vec-groups/block within one batch plane)
    int tb  = tarr[b];
    int tm1 = tb > 0 ? tb - 1 : 0;
    float A  = lab[tm1];          // log_alpha_bars[t-1]
    float Bv = l1ab[tm1] - LOGK;  // log_1m_alpha_bars[t-1] - log K
    float C  = la[tb];            // log_alphas[t]
    float D  = l1a[tb] - LOGK;    // log_1m_alphas[t] - log K
    bool  t0 = (tb == 0);

    const float4 xt0 = *reinterpret_cast<const float4*>(lxt + base);        // class 0
    const float4 xt1 = *reinterpret_cast<const float4*>(lxt + base + LL);   // class 1
    const float4 x00 = *reinterpret_cast<const float4*>(lx0 + base);
    const float4 x01 = *reinterpret_cast<const float4*>(lx0 + base + LL);

    float lt0[4] = {xt0.x, xt0.y, xt0.z, xt0.w};
    float lt1[4] = {xt1.x, xt1.y, xt1.z, xt1.w};
    float l00[4] = {x00.x, x00.y, x00.z, x00.w};
    float l01[4] = {x01.x, x01.y, x01.z, x01.w};
    float o0[4], o1[4];

#pragma unroll
    for (int i = 0; i < 4; ++i) {
        // q_pred(log_x_0, t-1), with t==0 passthrough
        float e0 = t0 ? l00[i] : lae(l00[i] + A, Bv);
        float e1 = t0 ? l01[i] : lae(l01[i] + A, Bv);
        // q_pred_one_step(log_x_t, t)
        float s0 = lae(lt0[i] + C, D);
        float s1 = lae(lt1[i] + C, D);
        float u0 = e0 + s0;
        float u1 = e1 + s1;
        // normalize over K=2
        float m   = fmaxf(u0, u1);
        float lse = m + __logf(1.0f + __expf(fminf(u0, u1) - m));
        o0[i] = u0 - lse;
        o1[i] = u1 - lse;
    }

    *reinterpret_cast<float4*>(out + base)      = make_float4(o0[0], o0[1], o0[2], o0[3]);
    *reinterpret_cast<float4*>(out + base + LL) = make_float4(o1[0], o1[1], o1[2], o1[3]);
}

extern "C" void kernel_launch(void* const* d_in, const int* in_sizes, int n_in,
                              void* d_out, int out_size, void* d_ws, size_t ws_size,
                              hipStream_t stream) {
    const float* lxt  = (const float*)d_in[0];
    const float* lx0  = (const float*)d_in[1];
    const float* la   = (const float*)d_in[2];
    const float* l1a  = (const float*)d_in[3];
    const float* lab  = (const float*)d_in[4];
    const float* l1ab = (const float*)d_in[5];
    const int*   tarr = (const int*)d_in[6];
    float*       out  = (float*)d_out;

    const int total_threads = B_DIM * VPB;   // 4,194,304 (one thread per 4 positions x 2 classes)
    const int block = 256;
    const int grid  = total_threads / block; // 16384

    qposterior_kernel<<<grid, block, 0, stream>>>(lxt, lx0, la, l1a, lab, l1ab, tarr, out);
}

// Round 5
// 299.418 us; speedup vs baseline: 1.0517x; 1.0517x over previous
//
#include <hip/hip_runtime.h>

// MultinomialDiffusion.q_posterior — structure-exploiting version.
//   log_x_t : (16,2,1,1024,1024) f32  LOG ONE-HOT  -> read plane 0 only, hot = (val > -35)
//   log_x_0 : (16,2,1,1024,1024) f32  log-softmax  -> read plane 0 only (plane1 = log(1-p))
//   schedules (1000,) f32; t (16,) int32; out (16,2,1,1024,1024) f32
// Per position (K=2):
//   p  = exp(l00)
//   e0 = log(a*p + c), e1 = log(a*(1-p) + c)      [t>0]   (a=alpha_bar[t-1], c=(1-a_bar)/2)
//   d  = e0 - e1   (or l00 - l01 when t==0)
//   Delta = d + (hot0 ? +delta : -delta),  delta = logaddexp(C,D) - D
//   o0 = -logaddexp(0, -Delta),  o1 = o0 - Delta
// Traffic: 128 MB read + 128 MB write. 5 transcendentals / position.

#define LL (1024 * 1024)
#define GPB (LL / 8)   // 8-position groups per batch plane = 131072

typedef float vfloat4 __attribute__((ext_vector_type(4)));  // native vector: OK for NT builtins

__global__ __launch_bounds__(256) void qposterior_kernel(
    const float* __restrict__ lxt,
    const float* __restrict__ lx0,
    const float* __restrict__ la,
    const float* __restrict__ l1a,
    const float* __restrict__ lab,
    const float* __restrict__ l1ab,
    const int* __restrict__ tarr,
    float* __restrict__ out)
{
    const float LOGK = 0.6931471805599453f; // log(2)

    int gid = blockIdx.x * blockDim.x + threadIdx.x;   // < 16 * 131072 = 2^21
    int b = gid >> 17;
    int v = gid & (GPB - 1);
    int base = b * (2 * LL) + v * 8;                   // element offset in plane 0

    // ---- per-batch scalars (wave-uniform: 512 blocks per batch) ----
    int tb = tarr[b];
    bool t0 = (tb == 0);
    float C = la[tb];
    float D = l1a[tb] - LOGK;
    float mm = fmaxf(C, D);
    float s_hot = mm + __logf(1.0f + __expf(fminf(C, D) - mm));
    float delta = s_hot - D;            // logaddexp(C,D) - D

    float a = 0.f, c = 0.f, apc = 0.f;
    if (!t0) {
        int tm1 = tb - 1;
        a   = __expf(lab[tm1]);           // alpha_bar[t-1]
        c   = 0.5f * __expf(l1ab[tm1]);   // (1 - alpha_bar[t-1]) / 2
        apc = a + c;
    }

    // ---- loads: plane 0 only (plus lx0 plane 1 for the rare t==0 batches) ----
    const vfloat4 xtA = *reinterpret_cast<const vfloat4*>(lxt + base);
    const vfloat4 xtB = *reinterpret_cast<const vfloat4*>(lxt + base + 4);
    const vfloat4 x0A = *reinterpret_cast<const vfloat4*>(lx0 + base);
    const vfloat4 x0B = *reinterpret_cast<const vfloat4*>(lx0 + base + 4);

    float xt0[8] = {xtA.x, xtA.y, xtA.z, xtA.w, xtB.x, xtB.y, xtB.z, xtB.w};
    float l00[8] = {x0A.x, x0A.y, x0A.z, x0A.w, x0B.x, x0B.y, x0B.z, x0B.w};
    float l01[8];
    if (t0) {
        const vfloat4 y0A = *reinterpret_cast<const vfloat4*>(lx0 + base + LL);
        const vfloat4 y0B = *reinterpret_cast<const vfloat4*>(lx0 + base + LL + 4);
        l01[0]=y0A.x; l01[1]=y0A.y; l01[2]=y0A.z; l01[3]=y0A.w;
        l01[4]=y0B.x; l01[5]=y0B.y; l01[6]=y0B.z; l01[7]=y0B.w;
    }

    float o0[8], o1[8];
#pragma unroll
    for (int i = 0; i < 8; ++i) {
        float d;
        if (t0) {
            d = l00[i] - l01[i];
        } else {
            float p  = __expf(l00[i]);
            float e0 = __logf(fmaf(a, p, c));
            float e1 = __logf(fmaf(-a, p, apc));
            d = e0 - e1;
        }
        float sd    = (xt0[i] > -35.0f) ? delta : -delta;
        float Delta = d + sd;
        // o0 = -logaddexp(0, -Delta) = -(max(0,-Delta) + log(1 + exp(-|Delta|)))
        float m  = fmaxf(-Delta, 0.0f);
        o0[i] = -(m + __logf(1.0f + __expf(-fabsf(Delta))));
        o1[i] = o0[i] - Delta;
    }

    vfloat4 r0A = {o0[0], o0[1], o0[2], o0[3]};
    vfloat4 r0B = {o0[4], o0[5], o0[6], o0[7]};
    vfloat4 r1A = {o1[0], o1[1], o1[2], o1[3]};
    vfloat4 r1B = {o1[4], o1[5], o1[6], o1[7]};

    // non-temporal stores: output is write-once, keep it from evicting inputs in L2/L3
    __builtin_nontemporal_store(r0A, reinterpret_cast<vfloat4*>(out + base));
    __builtin_nontemporal_store(r0B, reinterpret_cast<vfloat4*>(out + base + 4));
    __builtin_nontemporal_store(r1A, reinterpret_cast<vfloat4*>(out + base + LL));
    __builtin_nontemporal_store(r1B, reinterpret_cast<vfloat4*>(out + base + LL + 4));
}

extern "C" void kernel_launch(void* const* d_in, const int* in_sizes, int n_in,
                              void* d_out, int out_size, void* d_ws, size_t ws_size,
                              hipStream_t stream) {
    const float* lxt  = (const float*)d_in[0];
    const float* lx0  = (const float*)d_in[1];
    const float* la   = (const float*)d_in[2];
    const float* l1a  = (const float*)d_in[3];
    const float* lab  = (const float*)d_in[4];
    const float* l1ab = (const float*)d_in[5];
    const int*   tarr = (const int*)d_in[6];
    float*       out  = (float*)d_out;

    const int total_threads = 16 * GPB;      // 2,097,152 (8 positions x 2 classes each)
    const int block = 256;
    const int grid  = total_threads / block; // 8192

    qposterior_kernel<<<grid, block, 0, stream>>>(lxt, lx0, la, l1a, lab, l1ab, tarr, out);
}

// Round 6
// 292.324 us; speedup vs baseline: 1.0772x; 1.0243x over previous
//
#include <hip/hip_runtime.h>

// MultinomialDiffusion.q_posterior — structure-exploiting, fully-coalesced version.
//   log_x_t : (16,2,1,1024,1024) f32  LOG ONE-HOT  -> read plane 0 only, hot = (val > -35)
//   log_x_0 : (16,2,1,1024,1024) f32  log-softmax  -> read plane 0 only (plane1 = log(1-p))
//   schedules (1000,) f32; t (16,) int32; out (16,2,1,1024,1024) f32
// Math per position (K=2), a = alpha_bar[t-1], c = (1-alpha_bar[t-1])/2:
//   p  = exp(l00); e0 = log(a*p + c); e1 = log(a*(1-p) + c)     [t>0]
//   d  = e0 - e1   (or l00 - l01 when t==0)
//   Delta = d + (hot0 ? +delta : -delta),  delta = logaddexp(C,D) - D
//   o0 = -logaddexp(0, -Delta),  o1 = o0 - Delta
// Memory design: 4 streams (xt read, x0 read, out0 NT write, out1 NT write),
// ONE float4 per stream per iteration -> every instruction covers a contiguous
// 1KB across the wave (full 64B lines; NT store cannot amplify). 4 iterations
// per thread amortize scalar setup and keep ~8 VMEM ops in flight.

#define LL (1024 * 1024)
#define BLOCKS_PER_B 256              // 256 blocks x 256 thr x 4 iter x 4 elem = 2^20
#define ITER 4
#define STRIDE (BLOCKS_PER_B * 256)   // float4-groups per iteration step = 65536

typedef float vfloat4 __attribute__((ext_vector_type(4)));

__global__ __launch_bounds__(256) void qposterior_kernel(
    const float* __restrict__ lxt,
    const float* __restrict__ lx0,
    const float* __restrict__ la,
    const float* __restrict__ l1a,
    const float* __restrict__ lab,
    const float* __restrict__ l1ab,
    const int* __restrict__ tarr,
    float* __restrict__ out)
{
    const float LOGK = 0.6931471805599453f; // log(2)

    int bid   = blockIdx.x;
    int b     = bid >> 8;                 // 256 blocks per batch
    int local = bid & (BLOCKS_PER_B - 1);

    // ---- per-batch scalars (wave-uniform) ----
    int tb = tarr[b];
    bool t0 = (tb == 0);
    float C = la[tb];
    float D = l1a[tb] - LOGK;
    float mm = fmaxf(C, D);
    float s_hot = mm + __logf(1.0f + __expf(fminf(C, D) - mm));
    float delta = s_hot - D;              // logaddexp(C,D) - D

    float a = 0.f, c = 0.f, apc = 0.f;
    if (!t0) {
        int tm1 = tb - 1;
        a   = __expf(lab[tm1]);           // alpha_bar[t-1]
        c   = 0.5f * __expf(l1ab[tm1]);   // (1 - alpha_bar[t-1]) / 2
        apc = a + c;
    }

    const float* xt_p  = lxt + b * (2 * LL);
    const float* x0_p  = lx0 + b * (2 * LL);
    float*       out_p = out + b * (2 * LL);

    int g0 = local * 256 + threadIdx.x;   // float4-group index within batch plane

#pragma unroll
    for (int it = 0; it < ITER; ++it) {
        int e = (g0 + it * STRIDE) * 4;   // element offset in plane (max 2^20)

        vfloat4 xt = *reinterpret_cast<const vfloat4*>(xt_p + e);
        vfloat4 x0 = *reinterpret_cast<const vfloat4*>(x0_p + e);
        vfloat4 x1 = {0.f, 0.f, 0.f, 0.f};
        if (t0) x1 = *reinterpret_cast<const vfloat4*>(x0_p + e + LL);

        vfloat4 r0, r1;
#pragma unroll
        for (int i = 0; i < 4; ++i) {
            float l00 = x0[i];
            float d;
            if (t0) {
                d = l00 - x1[i];
            } else {
                float p  = __expf(l00);
                float e0 = __logf(fmaf(a, p, c));
                float e1 = __logf(fmaf(-a, p, apc));
                d = e0 - e1;
            }
            float sd    = (xt[i] > -35.0f) ? delta : -delta;
            float Delta = d + sd;
            // o0 = -logaddexp(0, -Delta)
            float m  = fmaxf(-Delta, 0.0f);
            float o0 = -(m + __logf(1.0f + __expf(-fabsf(Delta))));
            r0[i] = o0;
            r1[i] = o0 - Delta;
        }

        // NT stores: full-line coverage per instruction (lanes contiguous 16B),
        // keeps the 128MB output from evicting inputs out of L2/L3.
        __builtin_nontemporal_store(r0, reinterpret_cast<vfloat4*>(out_p + e));
        __builtin_nontemporal_store(r1, reinterpret_cast<vfloat4*>(out_p + e + LL));
    }
}

extern "C" void kernel_launch(void* const* d_in, const int* in_sizes, int n_in,
                              void* d_out, int out_size, void* d_ws, size_t ws_size,
                              hipStream_t stream) {
    const float* lxt  = (const float*)d_in[0];
    const float* lx0  = (const float*)d_in[1];
    const float* la   = (const float*)d_in[2];
    const float* l1a  = (const float*)d_in[3];
    const float* lab  = (const float*)d_in[4];
    const float* l1ab = (const float*)d_in[5];
    const int*   tarr = (const int*)d_in[6];
    float*       out  = (float*)d_out;

    const int grid  = 16 * BLOCKS_PER_B;  // 4096 blocks
    const int block = 256;

    qposterior_kernel<<<grid, block, 0, stream>>>(lxt, lx0, la, l1a, lab, l1ab, tarr, out);
}